// Round 6
// baseline (10759.364 us; speedup 1.0000x reference)
//
#include <hip/hip_runtime.h>

// MAF forward: 32 autoregressive MADE steps, fully fused. N=65536, D=32, H=1024, C=64.
// R5: register-chained GEMM1->tanh->GEMM2 (no hid LDS buffer, no mid barrier).
//   Trick: h is a reduction index for GEMM2, so W2's k-axis is stored PERMUTED
//   (phys h = 64w+16j+4lk+r  ->  q = 64w+32m+8lk+4jp+r, j=2m+jp) so each wave's
//   GEMM1 C-register tanh outputs ARE its GEMM2 A-fragments. Cross-wave K-reduction
//   via LDS atomicAdd into Pp[32][68]; epilogue reads + re-zeroes. 2 barriers/step.
//   W1/Wc/b1 pre-scaled by 2*log2(e) so tanh = 1 - 2*rcp(1+exp2(z)).
// ws layout (bf16 as u16):
//   [0      .. 32768)  W1mT  [h=1024][d=32]   = W1[d][h]*mask1 * 2log2e
//   [32768  .. 98304)  W2mTp [c=64][q=1024]   = W2[perm(q)][c]*mask2
//   [98304  ..163840)  WcT   [h=1024][c=64]   = Wc[c][h] * 2log2e

#define NS 65536
#define HH 1024
#define K2LOG2E 2.885390082f

typedef __attribute__((ext_vector_type(8))) short short8;
typedef __attribute__((ext_vector_type(4))) float f32x4;

__device__ inline unsigned short f2bf(float f) {
  unsigned int u = __builtin_bit_cast(unsigned int, f);
  u += 0x7fffu + ((u >> 16) & 1u);          // RNE
  return (unsigned short)(u >> 16);
}
__device__ inline unsigned int cvt_pk_bf16(float lo, float hi) {
  unsigned int r;
  asm("v_cvt_pk_bf16_f32 %0, %1, %2" : "=v"(r) : "v"(lo), "v"(hi));
  return r;
}
// input pre-scaled by 2log2e: tanh = 1 - 2/(1+exp2(z)); saturates for |z| large
__device__ inline float tanh_pre(float z) {
  float t = __builtin_amdgcn_exp2f(z);
  float r = __builtin_amdgcn_rcpf(t + 1.0f);
  return fmaf(-2.0f, r, 1.0f);
}

__global__ void maf_prep(const float* __restrict__ W1, const float* __restrict__ Wc,
                         const float* __restrict__ W2, unsigned short* __restrict__ ws) {
  int t = blockIdx.x * blockDim.x + threadIdx.x;     // 0 .. 163839
  if (t < 32768) {                                   // W1mT [h][d], scaled
    int h = t >> 5, d = t & 31;
    int deg = h % 31 + 1;                            // hid_deg
    float v = (deg >= d + 1) ? W1[(size_t)d * HH + h] * K2LOG2E : 0.f;
    ws[t] = f2bf(v);
  } else if (t < 98304) {                            // W2mTp [c][q], k-permuted
    int i = t - 32768;
    int c = i >> 10, q = i & 1023;
    int wv = q >> 6, m = (q >> 5) & 1, lk = (q >> 3) & 3, jp = (q >> 2) & 1, r = q & 3;
    int h = wv * 64 + (2 * m + jp) * 16 + 4 * lk + r;
    int deg = h % 31 + 1;
    float v = (((c >> 1) + 1) > deg) ? W2[(size_t)h * 64 + c] : 0.f;
    ws[t] = f2bf(v);
  } else {                                           // WcT [h][c], scaled
    int i = t - 98304;
    int h = i >> 6, c = i & 63;
    ws[t] = f2bf(Wc[(size_t)c * HH + h] * K2LOG2E);
  }
}

__global__ __launch_bounds__(1024, 4) void maf_main(
    const float* __restrict__ x, const float* __restrict__ ctx,
    const float* __restrict__ b1, const float* __restrict__ b2,
    const unsigned short* __restrict__ ws, float* __restrict__ out)
{
  // LDS: 2560 + 8704 = 11264 B
  __shared__ __align__(16) unsigned short ybf[32][40];  // y bf16 [s][d]
  __shared__ __align__(16) float Pp[32][68];            // P accumulation [s][c]

  const unsigned short* W1mT  = ws;            // [1024][32]
  const unsigned short* W2mTp = ws + 32768;    // [64][1024] (k-permuted)
  const unsigned short* WcT   = ws + 98304;    // [1024][64]

  const int tid  = threadIdx.x;
  const int lane = tid & 63;
  const int w    = tid >> 6;        // wave 0..15: owns h-chunk [64w, 64w+64)
  const int l15  = lane & 15;
  const int lk   = lane >> 4;       // 0..3
  const int s0   = blockIdx.x * 32;

  // zero y and Pp
  if (tid < 640) reinterpret_cast<unsigned int*>(&ybf[0][0])[tid] = 0u;
  for (int i = tid; i < 2176; i += 1024) (&Pp[0][0])[i] = 0.f;

  // ---- ctx B-fragments from global (f32 -> bf16 via cvt_pk) ----
  short8 cf[2][2];
#pragma unroll
  for (int sh = 0; sh < 2; ++sh)
#pragma unroll
    for (int kc = 0; kc < 2; ++kc) {
      const float* cp = ctx + (size_t)(s0 + sh * 16 + l15) * 64 + kc * 32 + lk * 8;
      f32x4 a = *reinterpret_cast<const f32x4*>(cp);
      f32x4 b = *reinterpret_cast<const f32x4*>(cp + 4);
      union { short8 s; unsigned int u[4]; } t;
      t.u[0] = cvt_pk_bf16(a[0], a[1]);
      t.u[1] = cvt_pk_bf16(a[2], a[3]);
      t.u[2] = cvt_pk_bf16(b[0], b[1]);
      t.u[3] = cvt_pk_bf16(b[2], b[3]);
      cf[sh][kc] = t.s;
    }

  // ---- WcH^T + b1 (both pre-scaled) for this wave's 64 h-rows; f32 (32 regs) ----
  f32x4 wch[2][4];
#pragma unroll
  for (int j = 0; j < 4; ++j) {
    int h0 = w * 64 + j * 16;
    f32x4 binit = *reinterpret_cast<const f32x4*>(b1 + h0 + 4 * lk);
    binit *= K2LOG2E;
#pragma unroll
    for (int sh = 0; sh < 2; ++sh) {
      f32x4 acc = binit;
#pragma unroll
      for (int kc = 0; kc < 2; ++kc) {
        short8 af = *reinterpret_cast<const short8*>(WcT + (size_t)(h0 + l15) * 64 + kc * 32 + lk * 8);
        acc = __builtin_amdgcn_mfma_f32_16x16x32_bf16(af, cf[sh][kc], acc, 0, 0, 0);
      }
      wch[sh][j] = acc;
    }
  }

  // ---- W1 A-fragments, register-resident (16 regs) ----
  short8 w1f[4];
#pragma unroll
  for (int j = 0; j < 4; ++j)
    w1f[j] = *reinterpret_cast<const short8*>(W1mT + (size_t)(w * 64 + j * 16 + l15) * 32 + lk * 8);

  // ---- W2 B-fragments for own h-chunk, all 64 c (32 regs): w2f[ct][m] ----
  short8 w2f[4][2];
#pragma unroll
  for (int ct = 0; ct < 4; ++ct)
#pragma unroll
    for (int m = 0; m < 2; ++m)
      w2f[ct][m] = *reinterpret_cast<const short8*>(
          W2mTp + (size_t)(16 * ct + l15) * 1024 + w * 64 + m * 32 + lk * 8);

  // ---- epilogue role: thread -> (sample se, dim de) ----
  const int se = tid >> 5, de = tid & 31;
  const float xv  = x[(size_t)(s0 + se) * 32 + de];
  const float b2e = b2[2 * de], b2o = b2[2 * de + 1];
  float ls_last = 0.f;

  __syncthreads();

#pragma unroll 1
  for (int step = 0; step < 32; ++step) {
    // ---- GEMM1 + tanh, all in registers; pa[sh][j] = packed bf16 hid frags ----
    short8 yb0 = *reinterpret_cast<const short8*>(&ybf[l15][lk * 8]);
    short8 yb1 = *reinterpret_cast<const short8*>(&ybf[16 + l15][lk * 8]);
    unsigned int pa[2][4][2];
#pragma unroll
    for (int j = 0; j < 4; ++j) {
      f32x4 c0 = __builtin_amdgcn_mfma_f32_16x16x32_bf16(w1f[j], yb0, wch[0][j], 0, 0, 0);
      f32x4 c1 = __builtin_amdgcn_mfma_f32_16x16x32_bf16(w1f[j], yb1, wch[1][j], 0, 0, 0);
      pa[0][j][0] = cvt_pk_bf16(tanh_pre(c0[0]), tanh_pre(c0[1]));
      pa[0][j][1] = cvt_pk_bf16(tanh_pre(c0[2]), tanh_pre(c0[3]));
      pa[1][j][0] = cvt_pk_bf16(tanh_pre(c1[0]), tanh_pre(c1[1]));
      pa[1][j][1] = cvt_pk_bf16(tanh_pre(c1[2]), tanh_pre(c1[3]));
    }

    // ---- GEMM2 over own h-chunk straight from registers; reduce via LDS atomics ----
#pragma unroll
    for (int ct = 0; ct < 4; ++ct) {
#pragma unroll
      for (int sh = 0; sh < 2; ++sh) {
        union { unsigned int u[4]; short8 s; } a0, a1;
        a0.u[0] = pa[sh][0][0]; a0.u[1] = pa[sh][0][1];
        a0.u[2] = pa[sh][1][0]; a0.u[3] = pa[sh][1][1];
        a1.u[0] = pa[sh][2][0]; a1.u[1] = pa[sh][2][1];
        a1.u[2] = pa[sh][3][0]; a1.u[3] = pa[sh][3][1];
        f32x4 acc = {0.f, 0.f, 0.f, 0.f};
        acc = __builtin_amdgcn_mfma_f32_16x16x32_bf16(a0.s, w2f[ct][0], acc, 0, 0, 0);
        acc = __builtin_amdgcn_mfma_f32_16x16x32_bf16(a1.s, w2f[ct][1], acc, 0, 0, 0);
#pragma unroll
        for (int r = 0; r < 4; ++r)
          atomicAdd(&Pp[16 * sh + 4 * lk + r][16 * ct + l15], acc[r]);
      }
    }
    __syncthreads();

    // ---- epilogue: thread (se, de): y = x*exp(ls) + sh; re-zero Pp ----
    {
      float2 v = *reinterpret_cast<const float2*>(&Pp[se][2 * de]);
      float shv = v.x + b2e;
      float lsv = v.y + b2o;
      float yv = fmaf(xv, __expf(lsv), shv);
      ybf[se][de] = f2bf(yv);
      float2 z = {0.f, 0.f};
      *reinterpret_cast<float2*>(&Pp[se][2 * de]) = z;   // same-address: ordered after read
      if (step == 31) {
        out[(size_t)(s0 + se) * 32 + de] = yv;
        ls_last = lsv;
      }
    }
    __syncthreads();
  }

  // ---- log_det: reduce ls over de within each 32-lane group ----
  float v = ls_last;
  v += __shfl_xor(v, 1);
  v += __shfl_xor(v, 2);
  v += __shfl_xor(v, 4);
  v += __shfl_xor(v, 8);
  v += __shfl_xor(v, 16);
  if (de == 0) out[(size_t)NS * 32 + s0 + se] = v;
}

extern "C" void kernel_launch(void* const* d_in, const int* in_sizes, int n_in,
                              void* d_out, int out_size, void* d_ws, size_t ws_size,
                              hipStream_t stream) {
  (void)in_sizes; (void)n_in; (void)out_size; (void)ws_size;
  const float* x   = (const float*)d_in[0];
  const float* ctx = (const float*)d_in[1];
  const float* W1  = (const float*)d_in[2];
  const float* b1  = (const float*)d_in[3];
  const float* Wc  = (const float*)d_in[4];
  const float* W2  = (const float*)d_in[5];
  const float* b2  = (const float*)d_in[6];
  unsigned short* ws = (unsigned short*)d_ws;
  float* out = (float*)d_out;

  maf_prep<<<640, 256, 0, stream>>>(W1, Wc, W2, ws);
  maf_main<<<2048, 1024, 0, stream>>>(x, ctx, b1, b2, ws, out);
}

// Round 7
// 772.141 us; speedup vs baseline: 13.9344x; 13.9344x over previous
//
#include <hip/hip_runtime.h>

// MAF forward: 32 autoregressive MADE steps, fully fused. N=65536, D=32, H=1024, C=64.
// R6 = R5 (register-chained GEMM1->tanh->GEMM2, W2 k-permuted, 2 barriers/step)
//      with the LDS-atomic reduction replaced by plain per-wave-slice ds_writes
//      (Ppw[16][32][68], conflict-free) + a 16-way read-reduce in the epilogue.
// ws layout (bf16 as u16):
//   [0      .. 32768)  W1mT  [h=1024][d=32]   = W1[d][h]*mask1 * 2log2e
//   [32768  .. 98304)  W2mTp [c=64][q=1024]   = W2[perm(q)][c]*mask2
//   [98304  ..163840)  WcT   [h=1024][c=64]   = Wc[c][h] * 2log2e

#define NS 65536
#define HH 1024
#define K2LOG2E 2.885390082f

typedef __attribute__((ext_vector_type(8))) short short8;
typedef __attribute__((ext_vector_type(4))) float f32x4;

__device__ inline unsigned short f2bf(float f) {
  unsigned int u = __builtin_bit_cast(unsigned int, f);
  u += 0x7fffu + ((u >> 16) & 1u);          // RNE
  return (unsigned short)(u >> 16);
}
__device__ inline unsigned int cvt_pk_bf16(float lo, float hi) {
  unsigned int r;
  asm("v_cvt_pk_bf16_f32 %0, %1, %2" : "=v"(r) : "v"(lo), "v"(hi));
  return r;
}
// input pre-scaled by 2log2e: tanh = 1 - 2/(1+exp2(z)); saturates for |z| large
__device__ inline float tanh_pre(float z) {
  float t = __builtin_amdgcn_exp2f(z);
  float r = __builtin_amdgcn_rcpf(t + 1.0f);
  return fmaf(-2.0f, r, 1.0f);
}

__global__ void maf_prep(const float* __restrict__ W1, const float* __restrict__ Wc,
                         const float* __restrict__ W2, unsigned short* __restrict__ ws) {
  int t = blockIdx.x * blockDim.x + threadIdx.x;     // 0 .. 163839
  if (t < 32768) {                                   // W1mT [h][d], scaled
    int h = t >> 5, d = t & 31;
    int deg = h % 31 + 1;                            // hid_deg
    float v = (deg >= d + 1) ? W1[(size_t)d * HH + h] * K2LOG2E : 0.f;
    ws[t] = f2bf(v);
  } else if (t < 98304) {                            // W2mTp [c][q], k-permuted
    int i = t - 32768;
    int c = i >> 10, q = i & 1023;
    int wv = q >> 6, m = (q >> 5) & 1, lk = (q >> 3) & 3, jp = (q >> 2) & 1, r = q & 3;
    int h = wv * 64 + (2 * m + jp) * 16 + 4 * lk + r;
    int deg = h % 31 + 1;
    float v = (((c >> 1) + 1) > deg) ? W2[(size_t)h * 64 + c] : 0.f;
    ws[t] = f2bf(v);
  } else {                                           // WcT [h][c], scaled
    int i = t - 98304;
    int h = i >> 6, c = i & 63;
    ws[t] = f2bf(Wc[(size_t)c * HH + h] * K2LOG2E);
  }
}

__global__ __launch_bounds__(1024, 4) void maf_main(
    const float* __restrict__ x, const float* __restrict__ ctx,
    const float* __restrict__ b1, const float* __restrict__ b2,
    const unsigned short* __restrict__ ws, float* __restrict__ out)
{
  // LDS: 2560 + 139264 = 141824 B -> 1 block/CU
  __shared__ __align__(16) unsigned short ybf[32][40];  // y bf16 [s][d]
  __shared__ __align__(16) float Ppw[16][32][68];       // per-wave P partials [w][s][c]

  const unsigned short* W1mT  = ws;            // [1024][32]
  const unsigned short* W2mTp = ws + 32768;    // [64][1024] (k-permuted)
  const unsigned short* WcT   = ws + 98304;    // [1024][64]

  const int tid  = threadIdx.x;
  const int lane = tid & 63;
  const int w    = tid >> 6;        // wave 0..15: owns h-chunk [64w, 64w+64)
  const int l15  = lane & 15;
  const int lk   = lane >> 4;       // 0..3
  const int s0   = blockIdx.x * 32;

  // zero y
  if (tid < 640) reinterpret_cast<unsigned int*>(&ybf[0][0])[tid] = 0u;

  // ---- ctx B-fragments from global (f32 -> bf16 via cvt_pk) ----
  short8 cf[2][2];
#pragma unroll
  for (int sh = 0; sh < 2; ++sh)
#pragma unroll
    for (int kc = 0; kc < 2; ++kc) {
      const float* cp = ctx + (size_t)(s0 + sh * 16 + l15) * 64 + kc * 32 + lk * 8;
      f32x4 a = *reinterpret_cast<const f32x4*>(cp);
      f32x4 b = *reinterpret_cast<const f32x4*>(cp + 4);
      union { short8 s; unsigned int u[4]; } t;
      t.u[0] = cvt_pk_bf16(a[0], a[1]);
      t.u[1] = cvt_pk_bf16(a[2], a[3]);
      t.u[2] = cvt_pk_bf16(b[0], b[1]);
      t.u[3] = cvt_pk_bf16(b[2], b[3]);
      cf[sh][kc] = t.s;
    }

  // ---- WcH^T + b1 (both pre-scaled) for this wave's 64 h-rows; f32 (32 regs) ----
  f32x4 wch[2][4];
#pragma unroll
  for (int j = 0; j < 4; ++j) {
    int h0 = w * 64 + j * 16;
    f32x4 binit = *reinterpret_cast<const f32x4*>(b1 + h0 + 4 * lk);
    binit *= K2LOG2E;
#pragma unroll
    for (int sh = 0; sh < 2; ++sh) {
      f32x4 acc = binit;
#pragma unroll
      for (int kc = 0; kc < 2; ++kc) {
        short8 af = *reinterpret_cast<const short8*>(WcT + (size_t)(h0 + l15) * 64 + kc * 32 + lk * 8);
        acc = __builtin_amdgcn_mfma_f32_16x16x32_bf16(af, cf[sh][kc], acc, 0, 0, 0);
      }
      wch[sh][j] = acc;
    }
  }

  // ---- W1 A-fragments, register-resident (16 regs) ----
  short8 w1f[4];
#pragma unroll
  for (int j = 0; j < 4; ++j)
    w1f[j] = *reinterpret_cast<const short8*>(W1mT + (size_t)(w * 64 + j * 16 + l15) * 32 + lk * 8);

  // ---- W2 B-fragments for own h-chunk, all 64 c (32 regs): w2f[ct][m] ----
  short8 w2f[4][2];
#pragma unroll
  for (int ct = 0; ct < 4; ++ct)
#pragma unroll
    for (int m = 0; m < 2; ++m)
      w2f[ct][m] = *reinterpret_cast<const short8*>(
          W2mTp + (size_t)(16 * ct + l15) * 1024 + w * 64 + m * 32 + lk * 8);

  // ---- epilogue role: thread -> (sample se, dim de) ----
  const int se = tid >> 5, de = tid & 31;
  const float xv  = x[(size_t)(s0 + se) * 32 + de];
  const float b2e = b2[2 * de], b2o = b2[2 * de + 1];
  float ls_last = 0.f;

  __syncthreads();

#pragma unroll 1
  for (int step = 0; step < 32; ++step) {
    // ---- GEMM1 + tanh, all in registers; pa[sh][j] = packed bf16 hid frags ----
    short8 yb0 = *reinterpret_cast<const short8*>(&ybf[l15][lk * 8]);
    short8 yb1 = *reinterpret_cast<const short8*>(&ybf[16 + l15][lk * 8]);
    unsigned int pa[2][4][2];
#pragma unroll
    for (int j = 0; j < 4; ++j) {
      f32x4 c0 = __builtin_amdgcn_mfma_f32_16x16x32_bf16(w1f[j], yb0, wch[0][j], 0, 0, 0);
      f32x4 c1 = __builtin_amdgcn_mfma_f32_16x16x32_bf16(w1f[j], yb1, wch[1][j], 0, 0, 0);
      pa[0][j][0] = cvt_pk_bf16(tanh_pre(c0[0]), tanh_pre(c0[1]));
      pa[0][j][1] = cvt_pk_bf16(tanh_pre(c0[2]), tanh_pre(c0[3]));
      pa[1][j][0] = cvt_pk_bf16(tanh_pre(c1[0]), tanh_pre(c1[1]));
      pa[1][j][1] = cvt_pk_bf16(tanh_pre(c1[2]), tanh_pre(c1[3]));
    }

    // ---- GEMM2 over own h-chunk from registers; plain writes to own Ppw slice ----
#pragma unroll
    for (int ct = 0; ct < 4; ++ct) {
#pragma unroll
      for (int sh = 0; sh < 2; ++sh) {
        union { unsigned int u[4]; short8 s; } a0, a1;
        a0.u[0] = pa[sh][0][0]; a0.u[1] = pa[sh][0][1];
        a0.u[2] = pa[sh][1][0]; a0.u[3] = pa[sh][1][1];
        a1.u[0] = pa[sh][2][0]; a1.u[1] = pa[sh][2][1];
        a1.u[2] = pa[sh][3][0]; a1.u[3] = pa[sh][3][1];
        f32x4 acc = {0.f, 0.f, 0.f, 0.f};
        acc = __builtin_amdgcn_mfma_f32_16x16x32_bf16(a0.s, w2f[ct][0], acc, 0, 0, 0);
        acc = __builtin_amdgcn_mfma_f32_16x16x32_bf16(a1.s, w2f[ct][1], acc, 0, 0, 0);
#pragma unroll
        for (int r = 0; r < 4; ++r)
          Ppw[w][16 * sh + 4 * lk + r][16 * ct + l15] = acc[r];
      }
    }
    __syncthreads();

    // ---- epilogue: thread (se, de): reduce 16 wave-slices, y = x*exp(ls)+sh ----
    {
      float shv = b2e, lsv = b2o;
#pragma unroll
      for (int q = 0; q < 16; ++q) {
        float2 v = *reinterpret_cast<const float2*>(&Ppw[q][se][2 * de]);
        shv += v.x; lsv += v.y;
      }
      float yv = fmaf(xv, __expf(lsv), shv);
      ybf[se][de] = f2bf(yv);
      if (step == 31) {
        out[(size_t)(s0 + se) * 32 + de] = yv;
        ls_last = lsv;
      }
    }
    __syncthreads();
  }

  // ---- log_det: reduce ls over de within each 32-lane group ----
  float v = ls_last;
  v += __shfl_xor(v, 1);
  v += __shfl_xor(v, 2);
  v += __shfl_xor(v, 4);
  v += __shfl_xor(v, 8);
  v += __shfl_xor(v, 16);
  if (de == 0) out[(size_t)NS * 32 + s0 + se] = v;
}

extern "C" void kernel_launch(void* const* d_in, const int* in_sizes, int n_in,
                              void* d_out, int out_size, void* d_ws, size_t ws_size,
                              hipStream_t stream) {
  (void)in_sizes; (void)n_in; (void)out_size; (void)ws_size;
  const float* x   = (const float*)d_in[0];
  const float* ctx = (const float*)d_in[1];
  const float* W1  = (const float*)d_in[2];
  const float* b1  = (const float*)d_in[3];
  const float* Wc  = (const float*)d_in[4];
  const float* W2  = (const float*)d_in[5];
  const float* b2  = (const float*)d_in[6];
  unsigned short* ws = (unsigned short*)d_ws;
  float* out = (float*)d_out;

  maf_prep<<<640, 256, 0, stream>>>(W1, Wc, W2, ws);
  maf_main<<<2048, 1024, 0, stream>>>(x, ctx, b1, b2, ws, out);
}